// Round 8
// baseline (1719.470 us; speedup 1.0000x reference)
//
#include <hip/hip_runtime.h>
#include <hip/hip_bf16.h>
#include <stdint.h>

#define T_TOK 2048
#define D_DIM 1024
#define E_EXP 64
#define K_TOP 8
#define H_DIM 256
#define ES_N  2
#define HS_DIM 2048

typedef __attribute__((ext_vector_type(8))) short bf16x8;
typedef __attribute__((ext_vector_type(4))) float f32x4;

__device__ __forceinline__ short f2bf(float f){
  union { float f; unsigned u; } v; v.f = f;
  unsigned r = v.u + 0x7FFFu + ((v.u >> 16) & 1u);
  return (short)(r >> 16);
}

__device__ __forceinline__ void gl_lds16(const void* g, void* l){
  __builtin_amdgcn_global_load_lds((const __attribute__((address_space(1))) void*)g,
                                   (__attribute__((address_space(3))) void*)l, 16, 0, 0);
}

// ---------------- kernel 1: x fp32 -> bf16, zero expert counters ----------------
__global__ __launch_bounds__(256) void k_prep(const float* __restrict__ x,
                                              short* __restrict__ xb,
                                              int* __restrict__ cnt){
  int gid = blockIdx.x * 256 + threadIdx.x;
  const float4* xv = (const float4*)x;
  float4 a = xv[gid*2+0];
  float4 b = xv[gid*2+1];
  bf16x8 o;
  o[0]=f2bf(a.x); o[1]=f2bf(a.y); o[2]=f2bf(a.z); o[3]=f2bf(a.w);
  o[4]=f2bf(b.x); o[5]=f2bf(b.y); o[6]=f2bf(b.z); o[7]=f2bf(b.w);
  *(bf16x8*)(xb + (size_t)gid*8) = o;
  if (blockIdx.x == 0 && threadIdx.x < E_EXP) cnt[threadIdx.x] = 0;
}

// ---------------- kernel 2: router (fp32), softmax + top8 + scatter ----------------
__global__ __launch_bounds__(256) void k_router(const float* __restrict__ x,
                                                const float* __restrict__ rw,
                                                const float* __restrict__ rb,
                                                int* __restrict__ cnt,
                                                int* __restrict__ btok,
                                                float* __restrict__ bw){
  int wv = threadIdx.x >> 6, lane = threadIdx.x & 63;
  int t0 = blockIdx.x * 16 + wv * 4;           // 4 tokens per wave
  float av[4];
  av[0]=av[1]=av[2]=av[3]=rb[lane];
  const float* x0 = x + (size_t)t0 * D_DIM;
  for (int d = 0; d < D_DIM; d += 4){
    float w0 = rw[(d+0)*E_EXP + lane];
    float w1 = rw[(d+1)*E_EXP + lane];
    float w2 = rw[(d+2)*E_EXP + lane];
    float w3 = rw[(d+3)*E_EXP + lane];
    float4 xa = *(const float4*)(x0 + 0*D_DIM + d);
    float4 xb4= *(const float4*)(x0 + 1*D_DIM + d);
    float4 xc = *(const float4*)(x0 + 2*D_DIM + d);
    float4 xd = *(const float4*)(x0 + 3*D_DIM + d);
    av[0] += xa.x*w0 + xa.y*w1 + xa.z*w2 + xa.w*w3;
    av[1] += xb4.x*w0 + xb4.y*w1 + xb4.z*w2 + xb4.w*w3;
    av[2] += xc.x*w0 + xc.y*w1 + xc.z*w2 + xc.w*w3;
    av[3] += xd.x*w0 + xd.y*w1 + xd.z*w2 + xd.w*w3;
  }
#pragma unroll
  for (int tt = 0; tt < 4; ++tt){
    float v = av[tt];
    float m = v;
#pragma unroll
    for (int o = 32; o; o >>= 1) m = fmaxf(m, __shfl_xor(m, o));
    float p = __expf(v - m);
    float s = p;
#pragma unroll
    for (int o = 32; o; o >>= 1) s += __shfl_xor(s, o);
    p /= s;                                     // prob of expert==lane
    float pw = p, wsum = 0.f, selv = 0.f;
    int seli = 0;
#pragma unroll
    for (int k = 0; k < K_TOP; ++k){
      unsigned long long pk =
        ((unsigned long long)__float_as_uint(pw) << 32) | (unsigned)(E_EXP - 1 - lane);
#pragma unroll
      for (int o = 32; o; o >>= 1){
        unsigned long long q = __shfl_xor(pk, o);
        pk = (pk > q) ? pk : q;
      }
      float bv = __uint_as_float((unsigned)(pk >> 32));
      int bi = E_EXP - 1 - (int)(pk & 0xffffffffULL);
      wsum += bv;
      if (lane == k){ selv = bv; seli = bi; }
      if (lane == bi) pw = 0.0f;                // mask out (probs are >0)
    }
    if (lane < K_TOP){
      int t = t0 + tt;
      int pos = atomicAdd(&cnt[seli], 1);
      btok[seli * T_TOK + pos] = t;
      bw  [seli * T_TOK + pos] = selv / wsum;
    }
  }
}

// ---------------- kernel 3: shared GEMM1 + SiLU -> hs (bf16) ----------------
// hs[es] = silu(x_bf16 @ sw1[es] + sb1[es])   M=2048 N=2048 K=1024, 128x128 tile
__global__ __launch_bounds__(256) void k_shared1(const short* __restrict__ xb,
                                                 const float* __restrict__ sw1,
                                                 const float* __restrict__ sb1,
                                                 short* __restrict__ hs){
  __shared__ short Al[128*64];    // [row][k] linear
  __shared__ short Bl[128*72];    // [n][k] pad 72
  int es  = blockIdx.z;
  int row0 = blockIdx.y * 128;
  int col0 = blockIdx.x * 128;
  const float* Bg = sw1 + (size_t)es * D_DIM * HS_DIM;
  int tid = threadIdx.x, lane = tid & 63, l15 = lane & 15, h = lane >> 4, wv = tid >> 6;
  int wr = (wv >> 1) * 64, wc = (wv & 1) * 64;
  f32x4 acc[4][4] = {};
  for (int kt = 0; kt < D_DIM/64; ++kt){
#pragma unroll
    for (int j = 0; j < 4; ++j){
      int c = tid + 256*j;                 // 1024 chunks of 8 bf16
      int r = c >> 3, kc = c & 7;
      gl_lds16(xb + (size_t)(row0 + r)*D_DIM + kt*64 + kc*8, Al + c*8);
    }
#pragma unroll 4
    for (int j = 0; j < 8; ++j){
      int c = tid + 256*j;                 // 2048 float4 tasks: 64k x 32n4
      int k = c >> 5, n4 = c & 31;
      float4 bv = *(const float4*)(Bg + (size_t)(kt*64 + k)*HS_DIM + col0 + n4*4);
      Bl[(n4*4+0)*72 + k] = f2bf(bv.x);
      Bl[(n4*4+1)*72 + k] = f2bf(bv.y);
      Bl[(n4*4+2)*72 + k] = f2bf(bv.z);
      Bl[(n4*4+3)*72 + k] = f2bf(bv.w);
    }
    __syncthreads();
#pragma unroll
    for (int ks = 0; ks < 2; ++ks){
      bf16x8 af[4], bfr[4];
#pragma unroll
      for (int mf = 0; mf < 4; ++mf)
        af[mf] = *(const bf16x8*)(Al + (wr + mf*16 + l15)*64 + ks*32 + h*8);
#pragma unroll
      for (int nf = 0; nf < 4; ++nf)
        bfr[nf] = *(const bf16x8*)(Bl + (wc + nf*16 + l15)*72 + ks*32 + h*8);
#pragma unroll
      for (int mf = 0; mf < 4; ++mf)
#pragma unroll
        for (int nf = 0; nf < 4; ++nf)
          acc[mf][nf] = __builtin_amdgcn_mfma_f32_16x16x32_bf16(af[mf], bfr[nf], acc[mf][nf], 0,0,0);
    }
    __syncthreads();
  }
  short* Hs = hs + (size_t)es * T_TOK * HS_DIM;
#pragma unroll
  for (int mf = 0; mf < 4; ++mf)
#pragma unroll
    for (int nf = 0; nf < 4; ++nf){
      int col = col0 + wc + nf*16 + l15;
      float bias = sb1[es*HS_DIM + col];
#pragma unroll
      for (int j = 0; j < 4; ++j){
        int row = row0 + wr + mf*16 + h*4 + j;
        float v = acc[mf][nf][j] + bias;
        v = v / (1.f + __expf(-v));
        Hs[(size_t)row * HS_DIM + col] = f2bf(v);
      }
    }
}

// ---------------- kernel 4: shared GEMM2 (sum both experts) -> out (fp32 store) ----------------
// out = hs[0]@sw2[0] + hs[1]@sw2[1] + sb2[0] + sb2[1]   M=2048 N=1024 K=2048x2, 128x64 tile
__global__ __launch_bounds__(256) void k_shared2(const short* __restrict__ hs,
                                                 const float* __restrict__ sw2,
                                                 const float* __restrict__ sb2,
                                                 float* __restrict__ out){
  __shared__ short Al[128*64];
  __shared__ short Bl[64*72];
  int row0 = blockIdx.y * 128;
  int col0 = blockIdx.x * 64;
  int tid = threadIdx.x, lane = tid & 63, l15 = lane & 15, h = lane >> 4, wv = tid >> 6;
  int wr = wv * 32;
  f32x4 acc[2][4] = {};
  for (int es = 0; es < ES_N; ++es){
    const short* Ag = hs + (size_t)es * T_TOK * HS_DIM;
    const float* Bg = sw2 + (size_t)es * HS_DIM * D_DIM;
    for (int kt = 0; kt < HS_DIM/64; ++kt){
#pragma unroll
      for (int j = 0; j < 4; ++j){
        int c = tid + 256*j;
        int r = c >> 3, kc = c & 7;
        gl_lds16(Ag + (size_t)(row0 + r)*HS_DIM + kt*64 + kc*8, Al + c*8);
      }
#pragma unroll
      for (int j = 0; j < 4; ++j){
        int c = tid + 256*j;               // 1024 tasks: 64k x 16n4
        int k = c >> 4, n4 = c & 15;
        float4 bv = *(const float4*)(Bg + (size_t)(kt*64 + k)*D_DIM + col0 + n4*4);
        Bl[(n4*4+0)*72 + k] = f2bf(bv.x);
        Bl[(n4*4+1)*72 + k] = f2bf(bv.y);
        Bl[(n4*4+2)*72 + k] = f2bf(bv.z);
        Bl[(n4*4+3)*72 + k] = f2bf(bv.w);
      }
      __syncthreads();
#pragma unroll
      for (int ks = 0; ks < 2; ++ks){
        bf16x8 af[2], bfr[4];
#pragma unroll
        for (int mf = 0; mf < 2; ++mf)
          af[mf] = *(const bf16x8*)(Al + (wr + mf*16 + l15)*64 + ks*32 + h*8);
#pragma unroll
        for (int nf = 0; nf < 4; ++nf)
          bfr[nf] = *(const bf16x8*)(Bl + (nf*16 + l15)*72 + ks*32 + h*8);
#pragma unroll
        for (int mf = 0; mf < 2; ++mf)
#pragma unroll
          for (int nf = 0; nf < 4; ++nf)
            acc[mf][nf] = __builtin_amdgcn_mfma_f32_16x16x32_bf16(af[mf], bfr[nf], acc[mf][nf], 0,0,0);
      }
      __syncthreads();
    }
  }
#pragma unroll
  for (int mf = 0; mf < 2; ++mf)
#pragma unroll
    for (int nf = 0; nf < 4; ++nf){
      int col = col0 + nf*16 + l15;
      float bias = sb2[col] + sb2[D_DIM + col];
#pragma unroll
      for (int j = 0; j < 4; ++j){
        int row = row0 + wr + mf*16 + h*4 + j;
        out[(size_t)row * D_DIM + col] = acc[mf][nf][j] + bias;
      }
    }
}

// ---------------- kernel 5: routed experts, fused two GEMMs + scatter-add ----------------
__global__ __launch_bounds__(256) void k_routed(const short* __restrict__ xb,
                                                const float* __restrict__ w1,
                                                const float* __restrict__ b1,
                                                const float* __restrict__ w2,
                                                const float* __restrict__ b2,
                                                const int* __restrict__ cnt,
                                                const int* __restrict__ btok,
                                                const float* __restrict__ bw,
                                                float* __restrict__ out){
  __shared__ short Al[64*64];
  __shared__ short Bl[256*72];
  __shared__ short Hl[64*264];
  __shared__ int   s_tok[64];
  __shared__ float s_w[64];
  int e = blockIdx.y, ti = blockIdx.x;
  int ne = cnt[e];
  if (ti * 64 >= ne) return;
  int nrows = min(64, ne - ti*64);
  int tid = threadIdx.x, lane = tid & 63, l15 = lane & 15, h = lane >> 4, wv = tid >> 6;
  if (tid < 64){
    int ok = tid < nrows;
    s_tok[tid] = ok ? btok[e*T_TOK + ti*64 + tid] : 0;
    s_w[tid]   = ok ? bw  [e*T_TOK + ti*64 + tid] : 0.f;
  }
  __syncthreads();
  // ---- phase 1: h[64][256] = silu(Xg @ W1 + b1) ----
  const float* W1g = w1 + (size_t)e * D_DIM * H_DIM;
  {
    f32x4 acc[4][4] = {};
    for (int kt = 0; kt < D_DIM/64; ++kt){
#pragma unroll
      for (int j = 0; j < 2; ++j){
        int c = tid + 256*j;               // 512 chunks (gathered rows)
        int r = c >> 3, kc = c & 7;
        gl_lds16(xb + (size_t)s_tok[r]*D_DIM + kt*64 + kc*8, Al + c*8);
      }
#pragma unroll 4
      for (int j = 0; j < 16; ++j){
        int c = tid + 256*j;               // 4096 tasks: 64k x 64n4
        int k = c >> 6, n4 = c & 63;
        float4 bv = *(const float4*)(W1g + (size_t)(kt*64 + k)*H_DIM + n4*4);
        Bl[(n4*4+0)*72 + k] = f2bf(bv.x);
        Bl[(n4*4+1)*72 + k] = f2bf(bv.y);
        Bl[(n4*4+2)*72 + k] = f2bf(bv.z);
        Bl[(n4*4+3)*72 + k] = f2bf(bv.w);
      }
      __syncthreads();
#pragma unroll
      for (int ks = 0; ks < 2; ++ks){
        bf16x8 af[4], bfr[4];
#pragma unroll
        for (int mf = 0; mf < 4; ++mf)
          af[mf] = *(const bf16x8*)(Al + (mf*16 + l15)*64 + ks*32 + h*8);
#pragma unroll
        for (int nf = 0; nf < 4; ++nf)
          bfr[nf] = *(const bf16x8*)(Bl + (wv*64 + nf*16 + l15)*72 + ks*32 + h*8);
#pragma unroll
        for (int mf = 0; mf < 4; ++mf)
#pragma unroll
          for (int nf = 0; nf < 4; ++nf)
            acc[mf][nf] = __builtin_amdgcn_mfma_f32_16x16x32_bf16(af[mf], bfr[nf], acc[mf][nf], 0,0,0);
      }
      __syncthreads();
    }
#pragma unroll
    for (int mf = 0; mf < 4; ++mf)
#pragma unroll
      for (int nf = 0; nf < 4; ++nf){
        int col = wv*64 + nf*16 + l15;
        float bias = b1[e*H_DIM + col];
#pragma unroll
        for (int j = 0; j < 4; ++j){
          int row = mf*16 + h*4 + j;
          float v = acc[mf][nf][j] + bias;
          v = v / (1.f + __expf(-v));
          Hl[row*264 + col] = f2bf(v);
        }
      }
  }
  __syncthreads();
  // ---- phase 2: out[tok] += cw * (h @ W2 + b2), in 4 chunks of 256 cols ----
  const float* W2g = w2 + (size_t)e * H_DIM * D_DIM;
  for (int nc = 0; nc < 4; ++nc){
    f32x4 a2[4][4] = {};
    for (int kk = 0; kk < 4; ++kk){
#pragma unroll 4
      for (int j = 0; j < 16; ++j){
        int c = tid + 256*j;               // 4096 tasks: 64k x 64n4
        int k = c >> 6, n4 = c & 63;
        float4 bv = *(const float4*)(W2g + (size_t)(kk*64 + k)*D_DIM + nc*256 + n4*4);
        Bl[(n4*4+0)*72 + k] = f2bf(bv.x);
        Bl[(n4*4+1)*72 + k] = f2bf(bv.y);
        Bl[(n4*4+2)*72 + k] = f2bf(bv.z);
        Bl[(n4*4+3)*72 + k] = f2bf(bv.w);
      }
      __syncthreads();
#pragma unroll
      for (int ks = 0; ks < 2; ++ks){
        bf16x8 af[4], bfr[4];
#pragma unroll
        for (int mf = 0; mf < 4; ++mf)
          af[mf] = *(const bf16x8*)(Hl + (mf*16 + l15)*264 + kk*64 + ks*32 + h*8);
#pragma unroll
        for (int nf = 0; nf < 4; ++nf)
          bfr[nf] = *(const bf16x8*)(Bl + (wv*64 + nf*16 + l15)*72 + ks*32 + h*8);
#pragma unroll
        for (int mf = 0; mf < 4; ++mf)
#pragma unroll
          for (int nf = 0; nf < 4; ++nf)
            a2[mf][nf] = __builtin_amdgcn_mfma_f32_16x16x32_bf16(af[mf], bfr[nf], a2[mf][nf], 0,0,0);
      }
      __syncthreads();
    }
#pragma unroll
    for (int mf = 0; mf < 4; ++mf)
#pragma unroll
      for (int j = 0; j < 4; ++j){
        int row = mf*16 + h*4 + j;
        if (row < nrows){
          int t = s_tok[row];
          float cw = s_w[row];
#pragma unroll
          for (int nf = 0; nf < 4; ++nf){
            int col = nc*256 + wv*64 + nf*16 + l15;
            float v = (a2[mf][nf][j] + b2[e*D_DIM + col]) * cw;
            unsafeAtomicAdd(&out[(size_t)t * D_DIM + col], v);
          }
        }
      }
  }
}

extern "C" void kernel_launch(void* const* d_in, const int* in_sizes, int n_in,
                              void* d_out, int out_size, void* d_ws, size_t ws_size,
                              hipStream_t stream) {
  (void)in_sizes; (void)n_in; (void)out_size; (void)ws_size;
  const float* x   = (const float*)d_in[0];
  const float* rw  = (const float*)d_in[1];
  const float* rb  = (const float*)d_in[2];
  const float* w1  = (const float*)d_in[3];
  const float* b1  = (const float*)d_in[4];
  const float* w2  = (const float*)d_in[5];
  const float* b2  = (const float*)d_in[6];
  const float* sw1 = (const float*)d_in[7];
  const float* sb1 = (const float*)d_in[8];
  const float* sw2 = (const float*)d_in[9];
  const float* sb2 = (const float*)d_in[10];
  float* out = (float*)d_out;

  char* w = (char*)d_ws;
  short* xb   = (short*)(w);                                  // 4 MB
  short* hs   = (short*)(w + (4u<<20));                       // 16 MB
  int*   cnt  = (int*)  (w + (20u<<20));                      // 256 B
  int*   btok = (int*)  (w + (20u<<20) + 1024);               // 512 KB
  float* bw   = (float*)(w + (20u<<20) + 1024 + (512u<<10));  // 512 KB

  k_prep   <<<dim3(1024),        256, 0, stream>>>(x, xb, cnt);
  k_router <<<dim3(128),         256, 0, stream>>>(x, rw, rb, cnt, btok, bw);
  k_shared1<<<dim3(16, 16, 2),   256, 0, stream>>>(xb, sw1, sb1, hs);
  k_shared2<<<dim3(16, 16),      256, 0, stream>>>(hs, sw2, sb2, out);
  k_routed <<<dim3(32, 64),      256, 0, stream>>>(xb, w1, b1, w2, b2, cnt, btok, bw, out);
}

// Round 11
// 561.061 us; speedup vs baseline: 3.0647x; 3.0647x over previous
//
#include <hip/hip_runtime.h>
#include <hip/hip_bf16.h>
#include <stdint.h>

#define T_TOK 2048
#define D_DIM 1024
#define E_EXP 64
#define K_TOP 8
#define H_DIM 256
#define ES_N  2
#define HS_DIM 2048

typedef __attribute__((ext_vector_type(8))) short bf16x8;
typedef __attribute__((ext_vector_type(4))) float f32x4;

__device__ __forceinline__ short f2bf(float f){
  union { float f; unsigned u; } v; v.f = f;
  unsigned r = v.u + 0x7FFFu + ((v.u >> 16) & 1u);
  return (short)(r >> 16);
}

__device__ __forceinline__ void gl_lds16(const void* g, void* l){
  __builtin_amdgcn_global_load_lds((const __attribute__((address_space(1))) void*)g,
                                   (__attribute__((address_space(3))) void*)l, 16, 0, 0);
}

// ---------------- kernel 1: x fp32 -> bf16, zero expert counters ----------------
__global__ __launch_bounds__(256) void k_prep(const float* __restrict__ x,
                                              short* __restrict__ xb,
                                              int* __restrict__ cnt){
  int gid = blockIdx.x * 256 + threadIdx.x;
  const float4* xv = (const float4*)x;
  float4 a = xv[gid*2+0];
  float4 b = xv[gid*2+1];
  bf16x8 o;
  o[0]=f2bf(a.x); o[1]=f2bf(a.y); o[2]=f2bf(a.z); o[3]=f2bf(a.w);
  o[4]=f2bf(b.x); o[5]=f2bf(b.y); o[6]=f2bf(b.z); o[7]=f2bf(b.w);
  *(bf16x8*)(xb + (size_t)gid*8) = o;
  if (blockIdx.x == 0 && threadIdx.x < E_EXP) cnt[threadIdx.x] = 0;
}

// ---------------- kernel 2: router (fp32), softmax + top8 + scatter ----------------
__global__ __launch_bounds__(256) void k_router(const float* __restrict__ x,
                                                const float* __restrict__ rw,
                                                const float* __restrict__ rb,
                                                int* __restrict__ cnt,
                                                int* __restrict__ btok,
                                                float* __restrict__ bw){
  int wv = threadIdx.x >> 6, lane = threadIdx.x & 63;
  int t0 = blockIdx.x * 16 + wv * 4;           // 4 tokens per wave
  float av[4];
  av[0]=av[1]=av[2]=av[3]=rb[lane];
  const float* x0 = x + (size_t)t0 * D_DIM;
  for (int d = 0; d < D_DIM; d += 4){
    float w0 = rw[(d+0)*E_EXP + lane];
    float w1 = rw[(d+1)*E_EXP + lane];
    float w2 = rw[(d+2)*E_EXP + lane];
    float w3 = rw[(d+3)*E_EXP + lane];
    float4 xa = *(const float4*)(x0 + 0*D_DIM + d);
    float4 xb4= *(const float4*)(x0 + 1*D_DIM + d);
    float4 xc = *(const float4*)(x0 + 2*D_DIM + d);
    float4 xd = *(const float4*)(x0 + 3*D_DIM + d);
    av[0] += xa.x*w0 + xa.y*w1 + xa.z*w2 + xa.w*w3;
    av[1] += xb4.x*w0 + xb4.y*w1 + xb4.z*w2 + xb4.w*w3;
    av[2] += xc.x*w0 + xc.y*w1 + xc.z*w2 + xc.w*w3;
    av[3] += xd.x*w0 + xd.y*w1 + xd.z*w2 + xd.w*w3;
  }
#pragma unroll
  for (int tt = 0; tt < 4; ++tt){
    float v = av[tt];
    float m = v;
#pragma unroll
    for (int o = 32; o; o >>= 1) m = fmaxf(m, __shfl_xor(m, o));
    float p = __expf(v - m);
    float s = p;
#pragma unroll
    for (int o = 32; o; o >>= 1) s += __shfl_xor(s, o);
    p /= s;
    float pw = p, wsum = 0.f, selv = 0.f;
    int seli = 0;
#pragma unroll
    for (int k = 0; k < K_TOP; ++k){
      unsigned long long pk =
        ((unsigned long long)__float_as_uint(pw) << 32) | (unsigned)(E_EXP - 1 - lane);
#pragma unroll
      for (int o = 32; o; o >>= 1){
        unsigned long long q = __shfl_xor(pk, o);
        pk = (pk > q) ? pk : q;
      }
      float bv = __uint_as_float((unsigned)(pk >> 32));
      int bi = E_EXP - 1 - (int)(pk & 0xffffffffULL);
      wsum += bv;
      if (lane == k){ selv = bv; seli = bi; }
      if (lane == bi) pw = 0.0f;
    }
    if (lane < K_TOP){
      int t = t0 + tt;
      int pos = atomicAdd(&cnt[seli], 1);
      btok[seli * T_TOK + pos] = t;
      bw  [seli * T_TOK + pos] = selv / wsum;
    }
  }
}

// ---------------- kernel 3: exclusive prefix sum of cnt -> off ----------------
__global__ __launch_bounds__(64) void k_scan(const int* __restrict__ cnt,
                                             int* __restrict__ off){
  int e = threadIdx.x;
  int s = 0;
  for (int i = 0; i < e; ++i) s += cnt[i];
  off[e] = s;
}

// ---------------- kernel 4: batched transpose + fp32->bf16 convert ----------------
// src: fp32 [B][K][N] row-major; dst: bf16 [B][N][K]. 64x64 tiles.
__global__ __launch_bounds__(256) void k_transcvt(const float* __restrict__ src,
                                                  short* __restrict__ dst,
                                                  int Kd, int Nd){
  __shared__ float T[64][68];
  int n0 = blockIdx.x * 64, k0 = blockIdx.y * 64;
  const float* S = src + (size_t)blockIdx.z * Kd * Nd;
  short*       Dp = dst + (size_t)blockIdx.z * Kd * Nd;
  int tid = threadIdx.x;
#pragma unroll
  for (int j = 0; j < 4; ++j){
    int c = tid + 256*j;                 // 1024 float4 tasks: 64 rows x 16 q
    int r = c >> 4, q = c & 15;
    float4 v = *(const float4*)(S + (size_t)(k0 + r)*Nd + n0 + q*4);
    T[r][q*4+0] = v.x; T[r][q*4+1] = v.y; T[r][q*4+2] = v.z; T[r][q*4+3] = v.w;
  }
  __syncthreads();
#pragma unroll
  for (int j = 0; j < 2; ++j){
    int c = tid + 256*j;                 // 512 chunks: 64 n-rows x 8 m-chunks
    int n = c >> 3, mc = c & 7;
    bf16x8 o;
#pragma unroll
    for (int i = 0; i < 8; ++i) o[i] = f2bf(T[mc*8+i][n]);
    *(bf16x8*)(Dp + (size_t)(n0 + n)*Kd + k0 + mc*8) = o;
  }
}

// ---------------- kernel 5: shared GEMM1 + SiLU -> hs (bf16) ----------------
// hs[es] = silu(x_bf16 @ sw1[es] + sb1[es])  via sw1t [es][n(HS)][k(D)]
__global__ __launch_bounds__(256) void k_shared1(const short* __restrict__ xb,
                                                 const short* __restrict__ sw1t,
                                                 const float* __restrict__ sb1,
                                                 short* __restrict__ hs){
  __shared__ short Al[128*64];
  __shared__ short Bl[128*64];
  int es  = blockIdx.z;
  int row0 = blockIdx.y * 128;
  int col0 = blockIdx.x * 128;
  const short* Bg = sw1t + (size_t)es * HS_DIM * D_DIM;
  int tid = threadIdx.x, lane = tid & 63, l15 = lane & 15, h = lane >> 4, wv = tid >> 6;
  int wr = (wv >> 1) * 64, wc = (wv & 1) * 64;
  f32x4 acc[4][4] = {};
  for (int kt = 0; kt < D_DIM/64; ++kt){
#pragma unroll
    for (int j = 0; j < 4; ++j){
      int c = tid + 256*j;
      int r = c >> 3, kc = c & 7;
      gl_lds16(xb + (size_t)(row0 + r)*D_DIM + kt*64 + kc*8, Al + c*8);
    }
#pragma unroll
    for (int j = 0; j < 4; ++j){
      int c = tid + 256*j;
      int r = c >> 3, kc = c & 7;
      gl_lds16(Bg + (size_t)(col0 + r)*D_DIM + kt*64 + kc*8, Bl + c*8);
    }
    __syncthreads();
#pragma unroll
    for (int ks = 0; ks < 2; ++ks){
      bf16x8 af[4], bfr[4];
#pragma unroll
      for (int mf = 0; mf < 4; ++mf)
        af[mf] = *(const bf16x8*)(Al + (wr + mf*16 + l15)*64 + ks*32 + h*8);
#pragma unroll
      for (int nf = 0; nf < 4; ++nf)
        bfr[nf] = *(const bf16x8*)(Bl + (wc + nf*16 + l15)*64 + ks*32 + h*8);
#pragma unroll
      for (int mf = 0; mf < 4; ++mf)
#pragma unroll
        for (int nf = 0; nf < 4; ++nf)
          acc[mf][nf] = __builtin_amdgcn_mfma_f32_16x16x32_bf16(af[mf], bfr[nf], acc[mf][nf], 0,0,0);
    }
    __syncthreads();
  }
  short* Hs = hs + (size_t)es * T_TOK * HS_DIM;
#pragma unroll
  for (int mf = 0; mf < 4; ++mf)
#pragma unroll
    for (int nf = 0; nf < 4; ++nf){
      int col = col0 + wc + nf*16 + l15;
      float bias = sb1[es*HS_DIM + col];
#pragma unroll
      for (int j = 0; j < 4; ++j){
        int row = row0 + wr + mf*16 + h*4 + j;
        float v = acc[mf][nf][j] + bias;
        v = v / (1.f + __expf(-v));
        Hs[(size_t)row * HS_DIM + col] = f2bf(v);
      }
    }
}

// ---------------- kernel 6: shared GEMM2 (sum both experts) -> out ----------------
// out = hs[0]@sw2[0] + hs[1]@sw2[1] + biases  via sw2t [es][n(D)][k(HS)]
__global__ __launch_bounds__(256) void k_shared2(const short* __restrict__ hs,
                                                 const short* __restrict__ sw2t,
                                                 const float* __restrict__ sb2,
                                                 float* __restrict__ out){
  __shared__ short Al[128*64];
  __shared__ short Bl[64*64];
  int row0 = blockIdx.y * 128;
  int col0 = blockIdx.x * 64;
  int tid = threadIdx.x, lane = tid & 63, l15 = lane & 15, h = lane >> 4, wv = tid >> 6;
  int wr = wv * 32;
  f32x4 acc[2][4] = {};
  for (int es = 0; es < ES_N; ++es){
    const short* Ag = hs + (size_t)es * T_TOK * HS_DIM;
    const short* Bg = sw2t + (size_t)es * D_DIM * HS_DIM;
    for (int kt = 0; kt < HS_DIM/64; ++kt){
#pragma unroll
      for (int j = 0; j < 4; ++j){
        int c = tid + 256*j;
        int r = c >> 3, kc = c & 7;
        gl_lds16(Ag + (size_t)(row0 + r)*HS_DIM + kt*64 + kc*8, Al + c*8);
      }
#pragma unroll
      for (int j = 0; j < 2; ++j){
        int c = tid + 256*j;
        int r = c >> 3, kc = c & 7;
        gl_lds16(Bg + (size_t)(col0 + r)*HS_DIM + kt*64 + kc*8, Bl + c*8);
      }
      __syncthreads();
#pragma unroll
      for (int ks = 0; ks < 2; ++ks){
        bf16x8 af[2], bfr[4];
#pragma unroll
        for (int mf = 0; mf < 2; ++mf)
          af[mf] = *(const bf16x8*)(Al + (wr + mf*16 + l15)*64 + ks*32 + h*8);
#pragma unroll
        for (int nf = 0; nf < 4; ++nf)
          bfr[nf] = *(const bf16x8*)(Bl + (nf*16 + l15)*64 + ks*32 + h*8);
#pragma unroll
        for (int mf = 0; mf < 2; ++mf)
#pragma unroll
          for (int nf = 0; nf < 4; ++nf)
            acc[mf][nf] = __builtin_amdgcn_mfma_f32_16x16x32_bf16(af[mf], bfr[nf], acc[mf][nf], 0,0,0);
      }
      __syncthreads();
    }
  }
#pragma unroll
  for (int mf = 0; mf < 2; ++mf)
#pragma unroll
    for (int nf = 0; nf < 4; ++nf){
      int col = col0 + nf*16 + l15;
      float bias = sb2[col] + sb2[D_DIM + col];
#pragma unroll
      for (int j = 0; j < 4; ++j){
        int row = row0 + wr + mf*16 + h*4 + j;
        out[(size_t)row * D_DIM + col] = acc[mf][nf][j] + bias;
      }
    }
}

// ---------------- kernel 7: routed GEMM1 -> hb (bucket-compact bf16) ----------------
// hb[off[e]+i][H] = silu(xb[tok]@w1[e]+b1[e])  via w1t [e][n(H)][k(D)]
__global__ __launch_bounds__(256) void k_routed1(const short* __restrict__ xb,
                                                 const short* __restrict__ w1t,
                                                 const float* __restrict__ b1,
                                                 const int* __restrict__ cnt,
                                                 const int* __restrict__ off,
                                                 const int* __restrict__ btok,
                                                 short* __restrict__ hb){
  __shared__ short Al[64*64];
  __shared__ short Bl[128*64];
  __shared__ int   s_tok[64];
  int e = blockIdx.x, ti = blockIdx.y, hc = blockIdx.z;
  int ne = cnt[e];
  if (ti * 64 >= ne) return;
  int nrows = min(64, ne - ti*64);
  int oe = off[e];
  int tid = threadIdx.x, lane = tid & 63, l15 = lane & 15, h = lane >> 4, wv = tid >> 6;
  int wr = (wv & 1) * 32, wc = (wv >> 1) * 64;
  if (tid < 64)
    s_tok[tid] = (tid < nrows) ? btok[e*T_TOK + ti*64 + tid] : 0;
  __syncthreads();
  const short* Bg = w1t + (size_t)e * H_DIM * D_DIM;
  f32x4 acc[2][4] = {};
  for (int kt = 0; kt < D_DIM/64; ++kt){
#pragma unroll
    for (int j = 0; j < 2; ++j){
      int c = tid + 256*j;
      int r = c >> 3, kc = c & 7;
      gl_lds16(xb + (size_t)s_tok[r]*D_DIM + kt*64 + kc*8, Al + c*8);
    }
#pragma unroll
    for (int j = 0; j < 4; ++j){
      int c = tid + 256*j;
      int r = c >> 3, kc = c & 7;
      gl_lds16(Bg + (size_t)(hc*128 + r)*D_DIM + kt*64 + kc*8, Bl + c*8);
    }
    __syncthreads();
#pragma unroll
    for (int ks = 0; ks < 2; ++ks){
      bf16x8 af[2], bfr[4];
#pragma unroll
      for (int mf = 0; mf < 2; ++mf)
        af[mf] = *(const bf16x8*)(Al + (wr + mf*16 + l15)*64 + ks*32 + h*8);
#pragma unroll
      for (int nf = 0; nf < 4; ++nf)
        bfr[nf] = *(const bf16x8*)(Bl + (wc + nf*16 + l15)*64 + ks*32 + h*8);
#pragma unroll
      for (int mf = 0; mf < 2; ++mf)
#pragma unroll
        for (int nf = 0; nf < 4; ++nf)
          acc[mf][nf] = __builtin_amdgcn_mfma_f32_16x16x32_bf16(af[mf], bfr[nf], acc[mf][nf], 0,0,0);
    }
    __syncthreads();
  }
#pragma unroll
  for (int mf = 0; mf < 2; ++mf)
#pragma unroll
    for (int nf = 0; nf < 4; ++nf){
      int col = hc*128 + wc + nf*16 + l15;
      float bias = b1[e*H_DIM + col];
#pragma unroll
      for (int j = 0; j < 4; ++j){
        int row = wr + mf*16 + h*4 + j;
        if (row < nrows){
          float v = acc[mf][nf][j] + bias;
          v = v / (1.f + __expf(-v));
          hb[(size_t)(oe + ti*64 + row) * H_DIM + col] = f2bf(v);
        }
      }
    }
}

// ---------------- kernel 8: routed GEMM2 + weighted scatter-add ----------------
// out[tok] += cw * (hb @ w2[e] + b2[e])  via w2t [e][n(D)][k(H)]
__global__ __launch_bounds__(256) void k_routed2(const short* __restrict__ hb,
                                                 const short* __restrict__ w2t,
                                                 const float* __restrict__ b2,
                                                 const int* __restrict__ cnt,
                                                 const int* __restrict__ off,
                                                 const int* __restrict__ btok,
                                                 const float* __restrict__ bw,
                                                 float* __restrict__ out){
  __shared__ short Al[64*64];
  __shared__ short Bl[256*64];
  __shared__ int   s_tok[64];
  __shared__ float s_w[64];
  int e = blockIdx.x, ti = blockIdx.y, nc = blockIdx.z;
  int ne = cnt[e];
  if (ti * 64 >= ne) return;
  int nrows = min(64, ne - ti*64);
  int oe = off[e];
  int tid = threadIdx.x, lane = tid & 63, l15 = lane & 15, h = lane >> 4, wv = tid >> 6;
  int wc = wv * 64;
  if (tid < 64){
    int ok = tid < nrows;
    s_tok[tid] = ok ? btok[e*T_TOK + ti*64 + tid] : 0;
    s_w[tid]   = ok ? bw  [e*T_TOK + ti*64 + tid] : 0.f;
  }
  __syncthreads();
  const short* Bg = w2t + (size_t)e * D_DIM * H_DIM;
  f32x4 acc[4][4] = {};
  for (int kk = 0; kk < H_DIM/64; ++kk){
#pragma unroll
    for (int j = 0; j < 2; ++j){
      int c = tid + 256*j;
      int r = c >> 3, kc = c & 7;
      gl_lds16(hb + (size_t)(oe + ti*64 + r)*H_DIM + kk*64 + kc*8, Al + c*8);
    }
#pragma unroll
    for (int j = 0; j < 8; ++j){
      int c = tid + 256*j;
      int r = c >> 3, kc = c & 7;
      gl_lds16(Bg + (size_t)(nc*256 + r)*H_DIM + kk*64 + kc*8, Bl + c*8);
    }
    __syncthreads();
#pragma unroll
    for (int ks = 0; ks < 2; ++ks){
      bf16x8 af[4], bfr[4];
#pragma unroll
      for (int mf = 0; mf < 4; ++mf)
        af[mf] = *(const bf16x8*)(Al + (mf*16 + l15)*64 + ks*32 + h*8);
#pragma unroll
      for (int nf = 0; nf < 4; ++nf)
        bfr[nf] = *(const bf16x8*)(Bl + (wc + nf*16 + l15)*64 + ks*32 + h*8);
#pragma unroll
      for (int mf = 0; mf < 4; ++mf)
#pragma unroll
        for (int nf = 0; nf < 4; ++nf)
          acc[mf][nf] = __builtin_amdgcn_mfma_f32_16x16x32_bf16(af[mf], bfr[nf], acc[mf][nf], 0,0,0);
    }
    __syncthreads();
  }
#pragma unroll
  for (int mf = 0; mf < 4; ++mf)
#pragma unroll
    for (int j = 0; j < 4; ++j){
      int row = mf*16 + h*4 + j;
      if (row < nrows){
        int t = s_tok[row];
        float cw = s_w[row];
#pragma unroll
        for (int nf = 0; nf < 4; ++nf){
          int col = nc*256 + wc + nf*16 + l15;
          float v = (acc[mf][nf][j] + b2[e*D_DIM + col]) * cw;
          unsafeAtomicAdd(&out[(size_t)t * D_DIM + col], v);
        }
      }
    }
}

extern "C" void kernel_launch(void* const* d_in, const int* in_sizes, int n_in,
                              void* d_out, int out_size, void* d_ws, size_t ws_size,
                              hipStream_t stream) {
  (void)in_sizes; (void)n_in; (void)out_size; (void)ws_size;
  const float* x   = (const float*)d_in[0];
  const float* rw  = (const float*)d_in[1];
  const float* rb  = (const float*)d_in[2];
  const float* w1  = (const float*)d_in[3];
  const float* b1  = (const float*)d_in[4];
  const float* w2  = (const float*)d_in[5];
  const float* b2  = (const float*)d_in[6];
  const float* sw1 = (const float*)d_in[7];
  const float* sb1 = (const float*)d_in[8];
  const float* sw2 = (const float*)d_in[9];
  const float* sb2 = (const float*)d_in[10];
  float* out = (float*)d_out;

  char* w = (char*)d_ws;                                      // layout (112 MB total)
  short* xb   = (short*)(w);                                  // 0   .. 4 MB
  short* hs   = (short*)(w + (4ull<<20));                     // 4   .. 20 MB
  int*   cnt  = (int*)  (w + (20ull<<20));                    // 256 B
  int*   off  = (int*)  (w + (20ull<<20) + 1024);             // 256 B
  int*   btok = (int*)  (w + (20ull<<20) + 2048);             // 512 KB
  float* bw   = (float*)(w + (20ull<<20) + 2048 + (512ull<<10)); // 512 KB
  short* hb   = (short*)(w + (22ull<<20));                    // 22 .. 30 MB (+2 MB guard)
  short* w1t  = (short*)(w + (32ull<<20));                    // 32  .. 64 MB
  short* w2t  = (short*)(w + (64ull<<20));                    // 64  .. 96 MB
  short* sw1t = (short*)(w + (96ull<<20));                    // 96  .. 104 MB
  short* sw2t = (short*)(w + (104ull<<20));                   // 104 .. 112 MB

  k_prep   <<<dim3(1024),        256, 0, stream>>>(x, xb, cnt);
  k_router <<<dim3(128),         256, 0, stream>>>(x, rw, rb, cnt, btok, bw);
  k_scan   <<<dim3(1),            64, 0, stream>>>(cnt, off);
  k_transcvt<<<dim3(4, 16, 64),  256, 0, stream>>>(w1,  w1t,  D_DIM,  H_DIM);
  k_transcvt<<<dim3(16, 4, 64),  256, 0, stream>>>(w2,  w2t,  H_DIM,  D_DIM);
  k_transcvt<<<dim3(32, 16, 2),  256, 0, stream>>>(sw1, sw1t, D_DIM,  HS_DIM);
  k_transcvt<<<dim3(16, 32, 2),  256, 0, stream>>>(sw2, sw2t, HS_DIM, D_DIM);
  k_shared1<<<dim3(16, 16, 2),   256, 0, stream>>>(xb, sw1t, sb1, hs);
  k_shared2<<<dim3(16, 16),      256, 0, stream>>>(hs, sw2t, sb2, out);
  k_routed1<<<dim3(64, 32, 2),   256, 0, stream>>>(xb, w1t, b1, cnt, off, btok, hb);
  k_routed2<<<dim3(64, 32, 4),   256, 0, stream>>>(hb, w2t, b2, cnt, off, btok, bw, out);
}

// Round 12
// 491.875 us; speedup vs baseline: 3.4957x; 1.1407x over previous
//
#include <hip/hip_runtime.h>
#include <hip/hip_bf16.h>
#include <stdint.h>

#define T_TOK 2048
#define D_DIM 1024
#define E_EXP 64
#define K_TOP 8
#define H_DIM 256
#define ES_N  2
#define HS_DIM 2048

typedef __attribute__((ext_vector_type(8))) short bf16x8;
typedef __attribute__((ext_vector_type(4))) float f32x4;

__device__ __forceinline__ short f2bf(float f){
  union { float f; unsigned u; } v; v.f = f;
  unsigned r = v.u + 0x7FFFu + ((v.u >> 16) & 1u);
  return (short)(r >> 16);
}

__device__ __forceinline__ void gl_lds16(const void* g, void* l){
  __builtin_amdgcn_global_load_lds((const __attribute__((address_space(1))) void*)g,
                                   (__attribute__((address_space(3))) void*)l, 16, 0, 0);
}

// ---------------- kernel 1: x fp32 -> bf16, zero expert counters ----------------
__global__ __launch_bounds__(256) void k_prep(const float* __restrict__ x,
                                              short* __restrict__ xb,
                                              int* __restrict__ cnt){
  int gid = blockIdx.x * 256 + threadIdx.x;
  const float4* xv = (const float4*)x;
  float4 a = xv[gid*2+0];
  float4 b = xv[gid*2+1];
  bf16x8 o;
  o[0]=f2bf(a.x); o[1]=f2bf(a.y); o[2]=f2bf(a.z); o[3]=f2bf(a.w);
  o[4]=f2bf(b.x); o[5]=f2bf(b.y); o[6]=f2bf(b.z); o[7]=f2bf(b.w);
  *(bf16x8*)(xb + (size_t)gid*8) = o;
  if (blockIdx.x == 0 && threadIdx.x < E_EXP) cnt[threadIdx.x] = 0;
}

// ---------------- kernel 2: router (fp32), 1 token/wave, softmax + top8 + scatter ----------------
// 512 blocks x 4 waves = 2048 waves (8/CU). lane = expert. Two FMA chains, unroll 8.
__global__ __launch_bounds__(256) void k_router(const float* __restrict__ x,
                                                const float* __restrict__ rw,
                                                const float* __restrict__ rb,
                                                int* __restrict__ cnt,
                                                int* __restrict__ btok,
                                                float* __restrict__ bw){
  int wv = threadIdx.x >> 6, lane = threadIdx.x & 63;
  int t = blockIdx.x * 4 + wv;                 // 1 token per wave
  const float* x0 = x + (size_t)t * D_DIM;
  float a0 = rb[lane], a1 = 0.f;
  for (int d = 0; d < D_DIM; d += 8){
    float w0 = rw[(d+0)*E_EXP + lane];
    float w1 = rw[(d+1)*E_EXP + lane];
    float w2 = rw[(d+2)*E_EXP + lane];
    float w3 = rw[(d+3)*E_EXP + lane];
    float w4 = rw[(d+4)*E_EXP + lane];
    float w5 = rw[(d+5)*E_EXP + lane];
    float w6 = rw[(d+6)*E_EXP + lane];
    float w7 = rw[(d+7)*E_EXP + lane];
    float4 xa = *(const float4*)(x0 + d);
    float4 xc = *(const float4*)(x0 + d + 4);
    a0 += xa.x*w0 + xa.y*w1 + xa.z*w2 + xa.w*w3;
    a1 += xc.x*w4 + xc.y*w5 + xc.z*w6 + xc.w*w7;
  }
  float v = a0 + a1;
  float m = v;
#pragma unroll
  for (int o = 32; o; o >>= 1) m = fmaxf(m, __shfl_xor(m, o));
  float p = __expf(v - m);
  float s = p;
#pragma unroll
  for (int o = 32; o; o >>= 1) s += __shfl_xor(s, o);
  p /= s;                                      // prob of expert==lane
  float pw = p, wsum = 0.f, selv = 0.f;
  int seli = 0;
#pragma unroll
  for (int k = 0; k < K_TOP; ++k){
    unsigned long long pk =
      ((unsigned long long)__float_as_uint(pw) << 32) | (unsigned)(E_EXP - 1 - lane);
#pragma unroll
    for (int o = 32; o; o >>= 1){
      unsigned long long q = __shfl_xor(pk, o);
      pk = (pk > q) ? pk : q;
    }
    float bv = __uint_as_float((unsigned)(pk >> 32));
    int bi = E_EXP - 1 - (int)(pk & 0xffffffffULL);
    wsum += bv;
    if (lane == k){ selv = bv; seli = bi; }
    if (lane == bi) pw = 0.0f;                 // mask out (probs are >0)
  }
  if (lane < K_TOP){
    int pos = atomicAdd(&cnt[seli], 1);
    btok[seli * T_TOK + pos] = t;
    bw  [seli * T_TOK + pos] = selv / wsum;
  }
}

// ---------------- kernel 3: exclusive prefix sum of cnt -> off ----------------
__global__ __launch_bounds__(64) void k_scan(const int* __restrict__ cnt,
                                             int* __restrict__ off){
  int e = threadIdx.x;
  int s = 0;
  for (int i = 0; i < e; ++i) s += cnt[i];
  off[e] = s;
}

// ---------------- kernel 4: batched transpose + fp32->bf16 convert ----------------
// src: fp32 [B][K][N] row-major; dst: bf16 [B][N][K]. 64x64 tiles.
__global__ __launch_bounds__(256) void k_transcvt(const float* __restrict__ src,
                                                  short* __restrict__ dst,
                                                  int Kd, int Nd){
  __shared__ float T[64][68];
  int n0 = blockIdx.x * 64, k0 = blockIdx.y * 64;
  const float* S = src + (size_t)blockIdx.z * Kd * Nd;
  short*       Dp = dst + (size_t)blockIdx.z * Kd * Nd;
  int tid = threadIdx.x;
#pragma unroll
  for (int j = 0; j < 4; ++j){
    int c = tid + 256*j;                 // 1024 float4 tasks: 64 rows x 16 q
    int r = c >> 4, q = c & 15;
    float4 v = *(const float4*)(S + (size_t)(k0 + r)*Nd + n0 + q*4);
    T[r][q*4+0] = v.x; T[r][q*4+1] = v.y; T[r][q*4+2] = v.z; T[r][q*4+3] = v.w;
  }
  __syncthreads();
#pragma unroll
  for (int j = 0; j < 2; ++j){
    int c = tid + 256*j;                 // 512 chunks: 64 n-rows x 8 m-chunks
    int n = c >> 3, mc = c & 7;
    bf16x8 o;
#pragma unroll
    for (int i = 0; i < 8; ++i) o[i] = f2bf(T[mc*8+i][n]);
    *(bf16x8*)(Dp + (size_t)(n0 + n)*Kd + k0 + mc*8) = o;
  }
}

// ---------------- kernel 5: shared GEMM1 + SiLU -> hs (bf16) ----------------
// hs[es] = silu(x_bf16 @ sw1[es] + sb1[es])  via sw1t [es][n(HS)][k(D)]
__global__ __launch_bounds__(256) void k_shared1(const short* __restrict__ xb,
                                                 const short* __restrict__ sw1t,
                                                 const float* __restrict__ sb1,
                                                 short* __restrict__ hs){
  __shared__ short Al[128*64];
  __shared__ short Bl[128*64];
  int es  = blockIdx.z;
  int row0 = blockIdx.y * 128;
  int col0 = blockIdx.x * 128;
  const short* Bg = sw1t + (size_t)es * HS_DIM * D_DIM;
  int tid = threadIdx.x, lane = tid & 63, l15 = lane & 15, h = lane >> 4, wv = tid >> 6;
  int wr = (wv >> 1) * 64, wc = (wv & 1) * 64;
  f32x4 acc[4][4] = {};
  for (int kt = 0; kt < D_DIM/64; ++kt){
#pragma unroll
    for (int j = 0; j < 4; ++j){
      int c = tid + 256*j;
      int r = c >> 3, kc = c & 7;
      gl_lds16(xb + (size_t)(row0 + r)*D_DIM + kt*64 + kc*8, Al + c*8);
    }
#pragma unroll
    for (int j = 0; j < 4; ++j){
      int c = tid + 256*j;
      int r = c >> 3, kc = c & 7;
      gl_lds16(Bg + (size_t)(col0 + r)*D_DIM + kt*64 + kc*8, Bl + c*8);
    }
    __syncthreads();
#pragma unroll
    for (int ks = 0; ks < 2; ++ks){
      bf16x8 af[4], bfr[4];
#pragma unroll
      for (int mf = 0; mf < 4; ++mf)
        af[mf] = *(const bf16x8*)(Al + (wr + mf*16 + l15)*64 + ks*32 + h*8);
#pragma unroll
      for (int nf = 0; nf < 4; ++nf)
        bfr[nf] = *(const bf16x8*)(Bl + (wc + nf*16 + l15)*64 + ks*32 + h*8);
#pragma unroll
      for (int mf = 0; mf < 4; ++mf)
#pragma unroll
        for (int nf = 0; nf < 4; ++nf)
          acc[mf][nf] = __builtin_amdgcn_mfma_f32_16x16x32_bf16(af[mf], bfr[nf], acc[mf][nf], 0,0,0);
    }
    __syncthreads();
  }
  short* Hs = hs + (size_t)es * T_TOK * HS_DIM;
#pragma unroll
  for (int mf = 0; mf < 4; ++mf)
#pragma unroll
    for (int nf = 0; nf < 4; ++nf){
      int col = col0 + wc + nf*16 + l15;
      float bias = sb1[es*HS_DIM + col];
#pragma unroll
      for (int j = 0; j < 4; ++j){
        int row = row0 + wr + mf*16 + h*4 + j;
        float v = acc[mf][nf][j] + bias;
        v = v / (1.f + __expf(-v));
        Hs[(size_t)row * HS_DIM + col] = f2bf(v);
      }
    }
}

// ---------------- kernel 6: shared GEMM2 (sum both experts) -> out ----------------
// out = hs[0]@sw2[0] + hs[1]@sw2[1] + biases  via sw2t [es][n(D)][k(HS)]
__global__ __launch_bounds__(256) void k_shared2(const short* __restrict__ hs,
                                                 const short* __restrict__ sw2t,
                                                 const float* __restrict__ sb2,
                                                 float* __restrict__ out){
  __shared__ short Al[128*64];
  __shared__ short Bl[64*64];
  int row0 = blockIdx.y * 128;
  int col0 = blockIdx.x * 64;
  int tid = threadIdx.x, lane = tid & 63, l15 = lane & 15, h = lane >> 4, wv = tid >> 6;
  int wr = wv * 32;
  f32x4 acc[2][4] = {};
  for (int es = 0; es < ES_N; ++es){
    const short* Ag = hs + (size_t)es * T_TOK * HS_DIM;
    const short* Bg = sw2t + (size_t)es * D_DIM * HS_DIM;
    for (int kt = 0; kt < HS_DIM/64; ++kt){
#pragma unroll
      for (int j = 0; j < 4; ++j){
        int c = tid + 256*j;
        int r = c >> 3, kc = c & 7;
        gl_lds16(Ag + (size_t)(row0 + r)*HS_DIM + kt*64 + kc*8, Al + c*8);
      }
#pragma unroll
      for (int j = 0; j < 2; ++j){
        int c = tid + 256*j;
        int r = c >> 3, kc = c & 7;
        gl_lds16(Bg + (size_t)(col0 + r)*HS_DIM + kt*64 + kc*8, Bl + c*8);
      }
      __syncthreads();
#pragma unroll
      for (int ks = 0; ks < 2; ++ks){
        bf16x8 af[2], bfr[4];
#pragma unroll
        for (int mf = 0; mf < 2; ++mf)
          af[mf] = *(const bf16x8*)(Al + (wr + mf*16 + l15)*64 + ks*32 + h*8);
#pragma unroll
        for (int nf = 0; nf < 4; ++nf)
          bfr[nf] = *(const bf16x8*)(Bl + (nf*16 + l15)*64 + ks*32 + h*8);
#pragma unroll
        for (int mf = 0; mf < 2; ++mf)
#pragma unroll
          for (int nf = 0; nf < 4; ++nf)
            acc[mf][nf] = __builtin_amdgcn_mfma_f32_16x16x32_bf16(af[mf], bfr[nf], acc[mf][nf], 0,0,0);
      }
      __syncthreads();
    }
  }
#pragma unroll
  for (int mf = 0; mf < 2; ++mf)
#pragma unroll
    for (int nf = 0; nf < 4; ++nf){
      int col = col0 + nf*16 + l15;
      float bias = sb2[col] + sb2[D_DIM + col];
#pragma unroll
      for (int j = 0; j < 4; ++j){
        int row = row0 + wr + mf*16 + h*4 + j;
        out[(size_t)row * D_DIM + col] = acc[mf][nf][j] + bias;
      }
    }
}

// ---------------- kernel 7: routed GEMM1 -> hb (bucket-compact bf16) ----------------
// hb[off[e]+i][H] = silu(xb[tok]@w1[e]+b1[e])  via w1t [e][n(H)][k(D)]
__global__ __launch_bounds__(256) void k_routed1(const short* __restrict__ xb,
                                                 const short* __restrict__ w1t,
                                                 const float* __restrict__ b1,
                                                 const int* __restrict__ cnt,
                                                 const int* __restrict__ off,
                                                 const int* __restrict__ btok,
                                                 short* __restrict__ hb){
  __shared__ short Al[64*64];
  __shared__ short Bl[128*64];
  __shared__ int   s_tok[64];
  int e = blockIdx.x, ti = blockIdx.y, hc = blockIdx.z;
  int ne = cnt[e];
  if (ti * 64 >= ne) return;
  int nrows = min(64, ne - ti*64);
  int oe = off[e];
  int tid = threadIdx.x, lane = tid & 63, l15 = lane & 15, h = lane >> 4, wv = tid >> 6;
  int wr = (wv & 1) * 32, wc = (wv >> 1) * 64;
  if (tid < 64)
    s_tok[tid] = (tid < nrows) ? btok[e*T_TOK + ti*64 + tid] : 0;
  __syncthreads();
  const short* Bg = w1t + (size_t)e * H_DIM * D_DIM;
  f32x4 acc[2][4] = {};
  for (int kt = 0; kt < D_DIM/64; ++kt){
#pragma unroll
    for (int j = 0; j < 2; ++j){
      int c = tid + 256*j;
      int r = c >> 3, kc = c & 7;
      gl_lds16(xb + (size_t)s_tok[r]*D_DIM + kt*64 + kc*8, Al + c*8);
    }
#pragma unroll
    for (int j = 0; j < 4; ++j){
      int c = tid + 256*j;
      int r = c >> 3, kc = c & 7;
      gl_lds16(Bg + (size_t)(hc*128 + r)*D_DIM + kt*64 + kc*8, Bl + c*8);
    }
    __syncthreads();
#pragma unroll
    for (int ks = 0; ks < 2; ++ks){
      bf16x8 af[2], bfr[4];
#pragma unroll
      for (int mf = 0; mf < 2; ++mf)
        af[mf] = *(const bf16x8*)(Al + (wr + mf*16 + l15)*64 + ks*32 + h*8);
#pragma unroll
      for (int nf = 0; nf < 4; ++nf)
        bfr[nf] = *(const bf16x8*)(Bl + (wc + nf*16 + l15)*64 + ks*32 + h*8);
#pragma unroll
      for (int mf = 0; mf < 2; ++mf)
#pragma unroll
        for (int nf = 0; nf < 4; ++nf)
          acc[mf][nf] = __builtin_amdgcn_mfma_f32_16x16x32_bf16(af[mf], bfr[nf], acc[mf][nf], 0,0,0);
    }
    __syncthreads();
  }
#pragma unroll
  for (int mf = 0; mf < 2; ++mf)
#pragma unroll
    for (int nf = 0; nf < 4; ++nf){
      int col = hc*128 + wc + nf*16 + l15;
      float bias = b1[e*H_DIM + col];
#pragma unroll
      for (int j = 0; j < 4; ++j){
        int row = wr + mf*16 + h*4 + j;
        if (row < nrows){
          float v = acc[mf][nf][j] + bias;
          v = v / (1.f + __expf(-v));
          hb[(size_t)(oe + ti*64 + row) * H_DIM + col] = f2bf(v);
        }
      }
    }
}

// ---------------- kernel 8: routed GEMM2 + weighted scatter-add ----------------
// out[tok] += cw * (hb @ w2[e] + b2[e])  via w2t [e][n(D)][k(H)]
__global__ __launch_bounds__(256) void k_routed2(const short* __restrict__ hb,
                                                 const short* __restrict__ w2t,
                                                 const float* __restrict__ b2,
                                                 const int* __restrict__ cnt,
                                                 const int* __restrict__ off,
                                                 const int* __restrict__ btok,
                                                 const float* __restrict__ bw,
                                                 float* __restrict__ out){
  __shared__ short Al[64*64];
  __shared__ short Bl[256*64];
  __shared__ int   s_tok[64];
  __shared__ float s_w[64];
  int e = blockIdx.x, ti = blockIdx.y, nc = blockIdx.z;
  int ne = cnt[e];
  if (ti * 64 >= ne) return;
  int nrows = min(64, ne - ti*64);
  int oe = off[e];
  int tid = threadIdx.x, lane = tid & 63, l15 = lane & 15, h = lane >> 4, wv = tid >> 6;
  int wc = wv * 64;
  if (tid < 64){
    int ok = tid < nrows;
    s_tok[tid] = ok ? btok[e*T_TOK + ti*64 + tid] : 0;
    s_w[tid]   = ok ? bw  [e*T_TOK + ti*64 + tid] : 0.f;
  }
  __syncthreads();
  const short* Bg = w2t + (size_t)e * D_DIM * H_DIM;
  f32x4 acc[4][4] = {};
  for (int kk = 0; kk < H_DIM/64; ++kk){
#pragma unroll
    for (int j = 0; j < 2; ++j){
      int c = tid + 256*j;
      int r = c >> 3, kc = c & 7;
      gl_lds16(hb + (size_t)(oe + ti*64 + r)*H_DIM + kk*64 + kc*8, Al + c*8);
    }
#pragma unroll
    for (int j = 0; j < 8; ++j){
      int c = tid + 256*j;
      int r = c >> 3, kc = c & 7;
      gl_lds16(Bg + (size_t)(nc*256 + r)*H_DIM + kk*64 + kc*8, Bl + c*8);
    }
    __syncthreads();
#pragma unroll
    for (int ks = 0; ks < 2; ++ks){
      bf16x8 af[4], bfr[4];
#pragma unroll
      for (int mf = 0; mf < 4; ++mf)
        af[mf] = *(const bf16x8*)(Al + (mf*16 + l15)*64 + ks*32 + h*8);
#pragma unroll
      for (int nf = 0; nf < 4; ++nf)
        bfr[nf] = *(const bf16x8*)(Bl + (wc + nf*16 + l15)*64 + ks*32 + h*8);
#pragma unroll
      for (int mf = 0; mf < 4; ++mf)
#pragma unroll
        for (int nf = 0; nf < 4; ++nf)
          acc[mf][nf] = __builtin_amdgcn_mfma_f32_16x16x32_bf16(af[mf], bfr[nf], acc[mf][nf], 0,0,0);
    }
    __syncthreads();
  }
#pragma unroll
  for (int mf = 0; mf < 4; ++mf)
#pragma unroll
    for (int j = 0; j < 4; ++j){
      int row = mf*16 + h*4 + j;
      if (row < nrows){
        int t = s_tok[row];
        float cw = s_w[row];
#pragma unroll
        for (int nf = 0; nf < 4; ++nf){
          int col = nc*256 + wc + nf*16 + l15;
          float v = (acc[mf][nf][j] + b2[e*D_DIM + col]) * cw;
          unsafeAtomicAdd(&out[(size_t)t * D_DIM + col], v);
        }
      }
    }
}

extern "C" void kernel_launch(void* const* d_in, const int* in_sizes, int n_in,
                              void* d_out, int out_size, void* d_ws, size_t ws_size,
                              hipStream_t stream) {
  (void)in_sizes; (void)n_in; (void)out_size; (void)ws_size;
  const float* x   = (const float*)d_in[0];
  const float* rw  = (const float*)d_in[1];
  const float* rb  = (const float*)d_in[2];
  const float* w1  = (const float*)d_in[3];
  const float* b1  = (const float*)d_in[4];
  const float* w2  = (const float*)d_in[5];
  const float* b2  = (const float*)d_in[6];
  const float* sw1 = (const float*)d_in[7];
  const float* sb1 = (const float*)d_in[8];
  const float* sw2 = (const float*)d_in[9];
  const float* sb2 = (const float*)d_in[10];
  float* out = (float*)d_out;

  char* w = (char*)d_ws;                                      // layout (112 MB total)
  short* xb   = (short*)(w);                                  // 0   .. 4 MB
  short* hs   = (short*)(w + (4ull<<20));                     // 4   .. 20 MB
  int*   cnt  = (int*)  (w + (20ull<<20));                    // 256 B
  int*   off  = (int*)  (w + (20ull<<20) + 1024);             // 256 B
  int*   btok = (int*)  (w + (20ull<<20) + 2048);             // 512 KB
  float* bw   = (float*)(w + (20ull<<20) + 2048 + (512ull<<10)); // 512 KB
  short* hb   = (short*)(w + (22ull<<20));                    // 22 .. 30 MB (+2 MB guard)
  short* w1t  = (short*)(w + (32ull<<20));                    // 32  .. 64 MB
  short* w2t  = (short*)(w + (64ull<<20));                    // 64  .. 96 MB
  short* sw1t = (short*)(w + (96ull<<20));                    // 96  .. 104 MB
  short* sw2t = (short*)(w + (104ull<<20));                   // 104 .. 112 MB

  k_prep   <<<dim3(1024),        256, 0, stream>>>(x, xb, cnt);
  k_router <<<dim3(512),         256, 0, stream>>>(x, rw, rb, cnt, btok, bw);
  k_scan   <<<dim3(1),            64, 0, stream>>>(cnt, off);
  k_transcvt<<<dim3(4, 16, 64),  256, 0, stream>>>(w1,  w1t,  D_DIM,  H_DIM);
  k_transcvt<<<dim3(16, 4, 64),  256, 0, stream>>>(w2,  w2t,  H_DIM,  D_DIM);
  k_transcvt<<<dim3(32, 16, 2),  256, 0, stream>>>(sw1, sw1t, D_DIM,  HS_DIM);
  k_transcvt<<<dim3(16, 32, 2),  256, 0, stream>>>(sw2, sw2t, HS_DIM, D_DIM);
  k_shared1<<<dim3(16, 16, 2),   256, 0, stream>>>(xb, sw1t, sb1, hs);
  k_shared2<<<dim3(16, 16),      256, 0, stream>>>(hs, sw2t, sb2, out);
  k_routed1<<<dim3(64, 32, 2),   256, 0, stream>>>(xb, w1t, b1, cnt, off, btok, hb);
  k_routed2<<<dim3(64, 32, 4),   256, 0, stream>>>(hb, w2t, b2, cnt, off, btok, bw, out);
}